// Round 12
// baseline (179.826 us; speedup 1.0000x reference)
//
#include <hip/hip_runtime.h>
#include <hip/hip_bf16.h>

// B=4, S=2048, D=512. fp32 in/out, bf16 MFMA internals.
// Key identity: multiplicative causal mask => E = 1 + F, F = expm1(scale*s) on
// the lower triangle (q>=k), 0 above. Then
//   out  = F @ vp'  +  T,   T[b,d] = sum_k vp'[b,k,d]
//   Z[k] = 2048 + colsum(F)
// Pipeline: cvt_all(+ZF0) | proj256 (q,k,v) | scores256 | scaleT | outF
//
// R11: 256^2 8-wave phase-split core for proj+scores (T3/T4/T5 structure).
//      Evidence: per-K-tile cost ~2700cyc vs ~1170 data floor + ~310 MFMA
//      floor = the m233 "2-phase is 72% stage/vmcnt/barrier overhead" symptom.
//      gemm256_core: BM=BN=256, BK=64, 512 thr (8 waves 2Mx4N, per-wave
//      128x64, acc[8][4]), LDS 128KB dynamic (1 block/CU), R4b's proven
//      two-barrier ledger at tile level + 4 sub-phases {ds_read, lgkmcnt(0),
//      setprio, 16 MFMA, barrier}. Same XOR-octet swizzle / glds16 staging
//      (0-conflict proven). proj = ONE launch, 192 blocks; scores = 144.
//      vpT projection back in proj => vb/Wvb revert to ws aliasing (the
//      R10 d_out scratch is no longer needed). outF/cvt/scale = R10.

#define S_LEN 2048
#define D_DIM 512
#define SCALE_F 0.044194173824159216f  // 1/sqrt(512)

typedef __attribute__((ext_vector_type(8))) short s8v;   // 8 bf16 = 4 VGPRs
typedef __attribute__((ext_vector_type(4))) short s4v;   // 4 bf16 = 8 B
typedef __attribute__((ext_vector_type(4))) float f4v;   // MFMA accumulator

enum { EPI_BIAS = 0, EPI_BIAS_T = 1, EPI_SCORES = 2 };

#define SBAR()    __builtin_amdgcn_s_barrier()
#define SCHEDB()  __builtin_amdgcn_sched_barrier(0)
#define WAITV(n)  asm volatile("s_waitcnt vmcnt(" #n ")")
#define WAITL0()  asm volatile("s_waitcnt lgkmcnt(0)")

__device__ __forceinline__ short f2bf_s(float f) {
  union { __hip_bfloat16 b; short s; } u; u.b = __float2bfloat16(f); return u.s;
}
__device__ __forceinline__ float bf2f_s(short h) {
  union { short s; __hip_bfloat16 b; } u; u.s = h; return __bfloat162float(u.b);
}

__device__ __forceinline__ void glds16(const short* g, short* l) {
  __builtin_amdgcn_global_load_lds((const __attribute__((address_space(1))) void*)g,
                                   (__attribute__((address_space(3))) void*)l, 16, 0, 0);
}

// LDS byte offset of a __shared__-derived pointer (addrspace(3) is 32-bit).
__device__ __forceinline__ unsigned lds_addr(const short* p) {
  return (unsigned)(unsigned long long)(const __attribute__((address_space(3))) short*)p;
}

// Inline-asm ds_read_b128: keeps the counted WAITV authoritative. MUST be
// followed by lgkmcnt(0)+SCHEDB before any consumer (rule 18).
__device__ __forceinline__ s8v dsr128(unsigned a) {
  s8v r;
  asm volatile("ds_read_b128 %0, %1" : "=&v"(r) : "v"(a));
  return r;
}

// ---------------------------------------------------------------------------
// 256x256 NT GEMM core, K=512 fixed (8 K-tiles of 64). 512 threads = 8 waves
// (wr=w>>2 in 0..1, wc=w&3 in 0..3); per-wave output 128x64; acc[8][4].
// LDS (dynamic, 128 KB): buf c at c*64KB; A = [256 rows][64 k] (32 KB),
// B at +32 KB. Staging: 4 glds16 rounds per operand (64 rows each).
// Per K-tile: [stage t+1 -> WAITV(8) -> SBAR] then 4 phases
// {ds_read A-pair (+B in ph0), lgkmcnt(0), setprio(1), 16 MFMA, SBAR}.
template <int EPI>
__device__ __forceinline__ void gemm256_core(
    const short* __restrict__ A, const short* __restrict__ B,
    short* __restrict__ C, const float* __restrict__ bias,
    short* SMEM, int N, size_t sCz, int m0, int n0, float* __restrict__ Z)
{
  const int tid  = threadIdx.x;          // 0..511
  const int w    = tid >> 6;             // 0..7
  const int lane = tid & 63;
  const int quad = lane >> 4;
  const int l16  = lane & 15;
  const int wr   = w >> 2;               // 0..1 -> M half
  const int wc   = w & 3;                // 0..3 -> N quarter

  const int strow = tid >> 3;                         // 0..63
  const int gl = ((tid & 7) ^ (strow & 7)) * 8;       // XOR column-octet swizzle
  const int t8 = tid * 8;
  const int swq = l16 & 7;

  f4v acc[8][4];
#pragma unroll
  for (int i = 0; i < 8; ++i)
#pragma unroll
    for (int j = 0; j < 4; ++j)
#pragma unroll
      for (int r = 0; r < 4; ++r) acc[i][j][r] = 0.0f;

  const short* Ag = A + (size_t)(m0 + strow) * 512 + gl;
  const short* Bg = B + (size_t)(n0 + strow) * 512 + gl;
  const size_t pstr = (size_t)64 * 512;   // 64 rows per staging round

  const unsigned base = lds_addr(SMEM);
  unsigned aoff[8], boff[4];
#pragma unroll
  for (int mf = 0; mf < 8; ++mf)
    aoff[mf] = base + (unsigned)((wr * 128 + mf * 16 + l16) * 128 + ((quad ^ swq) * 16));
#pragma unroll
  for (int nf = 0; nf < 4; ++nf)
    boff[nf] = base + 32768u + (unsigned)((wc * 64 + nf * 16 + l16) * 128 + ((quad ^ swq) * 16));

  // stage K-tile kt into LDS buffer b (8 glds16/thread: 4 A rounds + 4 B)
#define STG256(kt, b)                                                          \
  {                                                                            \
    short* dst_ = SMEM + (b) * 32768 + t8;                                     \
    const int ko_ = (kt) << 6;                                                 \
    _Pragma("unroll")                                                          \
    for (int p = 0; p < 4; ++p) glds16(Ag + ko_ + p * pstr, dst_ + p * 4096);  \
    _Pragma("unroll")                                                          \
    for (int p = 0; p < 4; ++p) glds16(Bg + ko_ + p * pstr, dst_ + 16384 + p * 4096); \
  }

  STG256(0, 0);

  for (int t = 0; t < 8; ++t) {
    const int c = t & 1;
    if (t < 7) {            // safe: end-barrier of tile t-1 fenced buf 1-c
      STG256(t + 1, 1 - c);
      SCHEDB();
      WAITV(8);             // tile t landed; tile t+1's 8 stay in flight
    } else {
      WAITV(0);
    }
    SBAR();
    SCHEDB();

    const unsigned cofs = (unsigned)(c << 16);   // c * 65536 bytes

    s8v bf[2][4];
#pragma unroll
    for (int kk = 0; kk < 2; ++kk)
#pragma unroll
      for (int nf = 0; nf < 4; ++nf)
        bf[kk][nf] = dsr128((boff[nf] ^ (unsigned)(kk << 6)) + cofs);

#pragma unroll
    for (int ph = 0; ph < 4; ++ph) {
      s8v af[2][2];
#pragma unroll
      for (int mi = 0; mi < 2; ++mi)
#pragma unroll
        for (int kk = 0; kk < 2; ++kk)
          af[mi][kk] = dsr128((aoff[ph * 2 + mi] ^ (unsigned)(kk << 6)) + cofs);
      WAITL0();
      SCHEDB();
      __builtin_amdgcn_s_setprio(1);
#pragma unroll
      for (int mi = 0; mi < 2; ++mi)
#pragma unroll
        for (int kk = 0; kk < 2; ++kk)
#pragma unroll
          for (int nf = 0; nf < 4; ++nf)
            acc[ph * 2 + mi][nf] =
                __builtin_amdgcn_mfma_f32_16x16x32_bf16(af[mi][kk], bf[kk][nf],
                                                        acc[ph * 2 + mi][nf], 0, 0, 0);
      __builtin_amdgcn_s_setprio(0);
      SBAR();               // phase-end; last one fences buf c for next STG
    }
  }
#undef STG256

  // ---- epilogue ----
  float bv[4];
  if (EPI == EPI_BIAS || EPI == EPI_BIAS_T) {
#pragma unroll
    for (int nf = 0; nf < 4; ++nf) bv[nf] = bias[n0 + wc * 64 + nf * 16 + l16];
  }

  if (EPI == EPI_BIAS_T) {
#pragma unroll
    for (int mf = 0; mf < 8; ++mf) {
#pragma unroll
      for (int nf = 0; nf < 4; ++nf) {
        const int gn  = n0 + wc * 64 + nf * 16 + l16;
        const int gmb = m0 + wr * 128 + mf * 16 + quad * 4;
        const int bb = gmb >> 11, ssb = gmb & (S_LEN - 1);
        s4v o;
#pragma unroll
        for (int r = 0; r < 4; ++r) o[r] = f2bf_s(acc[mf][nf][r] + bv[nf]);
        *(s4v*)&C[((size_t)bb * D_DIM + gn) * S_LEN + ssb] = o;
      }
    }
    return;
  }

  // EPI_BIAS / EPI_SCORES: LDS transpose -> coalesced 16B row stores.
  short* TB = SMEM;                 // 8 waves x 2176 shorts (32 rows x stride 68)
  const int wbase = w * 2176;
  float csum[4] = {0.f, 0.f, 0.f, 0.f};

#pragma unroll
  for (int ph = 0; ph < 4; ++ph) {
    __syncthreads();
#pragma unroll
    for (int ii = 0; ii < 2; ++ii) {
      const int mf = ph * 2 + ii;
#pragma unroll
      for (int nf = 0; nf < 4; ++nf) {
        const int gn = n0 + wc * 64 + nf * 16 + l16;
#pragma unroll
        for (int r = 0; r < 4; ++r) {
          short o;
          if (EPI == EPI_SCORES) {
            const int gm = m0 + wr * 128 + mf * 16 + quad * 4 + r;
            const float f = (gm >= gn) ? (__expf(acc[mf][nf][r] * SCALE_F) - 1.0f) : 0.0f;
            csum[nf] += f;
            o = f2bf_s(f);
          } else {
            o = f2bf_s(acc[mf][nf][r] + bv[nf]);
          }
          TB[wbase + (ii * 16 + quad * 4 + r) * 68 + nf * 16 + l16] = o;
        }
      }
    }
    __syncthreads();
#pragma unroll
    for (int p = 0; p < 4; ++p) {
      const int row = p * 8 + (lane >> 3);   // 0..31
      const int cg  = lane & 7;
      const s8v vv = *(const s8v*)&TB[wbase + row * 68 + cg * 8];
      const int gm = m0 + wr * 128 + ph * 32 + row;
      const int gn = n0 + wc * 64 + cg * 8;
      *(s8v*)&C[sCz + (size_t)gm * N + gn] = vv;
    }
  }

  if (EPI == EPI_SCORES) {
#pragma unroll
    for (int nf = 0; nf < 4; ++nf) {
      float cs = csum[nf];
      cs += __shfl_xor(cs, 16, 64);
      cs += __shfl_xor(cs, 32, 64);
      if (quad == 0) atomicAdd(&Z[n0 + wc * 64 + nf * 16 + l16], cs);
    }
  }
}

// All three projections, one launch: 192 blocks (8x24 XCD-bijective), 1/CU.
__global__ __launch_bounds__(512, 2) void proj256(
    const short* __restrict__ qb, const short* __restrict__ kb, const short* __restrict__ vb,
    const short* __restrict__ Wqb, const short* __restrict__ Wkb, const short* __restrict__ Wvb,
    short* __restrict__ qp, short* __restrict__ kp, short* __restrict__ vpT,
    const float* __restrict__ xq, const float* __restrict__ xk, const float* __restrict__ xv)
{
  extern __shared__ short SMEM[];               // 128 KB dynamic
  const int bid = blockIdx.x;
  const int bsw = (bid & 7) * 24 + (bid >> 3);  // 192 = 8x24
  const int z   = bsw >> 6;                     // 0..2
  const int rem = bsw & 63;
  const int m0  = (rem >> 1) * 256;
  const int n0  = (rem & 1) * 256;
  const short* A = (z == 0) ? qb : (z == 1) ? kb : vb;
  const short* B = (z == 0) ? Wqb : (z == 1) ? Wkb : Wvb;
  short*       C = (z == 0) ? qp : (z == 1) ? kp : vpT;
  const float* bias = (z == 0) ? xq : (z == 1) ? xk : xv;
  if (z == 2)
    gemm256_core<EPI_BIAS_T>(A, B, C, bias, SMEM, D_DIM, 0, m0, n0, nullptr);
  else
    gemm256_core<EPI_BIAS>(A, B, C, bias, SMEM, D_DIM, 0, m0, n0, nullptr);
}

// scores: 144 blocks (8x18 XCD-bijective): 36 lower-tri 256-tiles x 4 batches.
__global__ __launch_bounds__(512, 2) void scores256(
    const short* __restrict__ qp, const short* __restrict__ kp, short* __restrict__ F,
    float* __restrict__ Z)
{
  extern __shared__ short SMEM[];               // 128 KB dynamic
  const int bid = blockIdx.x;
  const int bsw = (bid & 7) * 18 + (bid >> 3);  // 144 = 8x18
  const int bz  = bsw / 36;
  const int t   = bsw - bz * 36;
  int ti = (int)((sqrtf(8.0f * t + 1.0f) - 1.0f) * 0.5f);
  while ((ti + 1) * (ti + 2) / 2 <= t) ++ti;
  while (ti * (ti + 1) / 2 > t) --ti;
  const int tj = t - ti * (ti + 1) / 2;         // tj <= ti
  gemm256_core<EPI_SCORES>(qp + (size_t)bz * S_LEN * D_DIM, kp + (size_t)bz * S_LEN * D_DIM,
                           F, nullptr, SMEM, S_LEN,
                           (size_t)bz * S_LEN * S_LEN, ti * 256, tj * 256,
                           Z + (bz << 11));
}

// out = F @ vpT'^T + T, 64x128 tiles, BK=64, K truncated at m0+64,
// triple-buffered (72 KB), prefetch distance 2 issued AFTER the barrier.
// Grid 512 1-D: h -> n0=(h&3)*128, bz=(h>>2)&3, zs=h>>4; co-resident pairs
// (h, h+256) get complementary niter (sum 33); long blocks dispatch first.
__global__ __launch_bounds__(256, 2) void gemm_outF(
    const short* __restrict__ F, const short* __restrict__ vpT,
    const float* __restrict__ Tv, float* __restrict__ out)
{
  __shared__ __align__(16) short SMEM[36864];   // 72 KB

  const int tid  = threadIdx.x;
  const int h    = blockIdx.x;
  const int n0   = (h & 3) * 128;
  const int bz   = (h >> 2) & 3;
  const int zs   = h >> 4;                      // 0..31
  const int mi   = (zs < 16) ? (31 - zs) : (zs - 16);
  const int m0   = mi * 64;

  const short* A = F   + (size_t)bz * S_LEN * S_LEN;
  const short* B = vpT + (size_t)bz * D_DIM * S_LEN;

  const int w    = tid >> 6;
  const int lane = tid & 63;
  const int quad = lane >> 4;
  const int l16  = lane & 15;
  const int wm   = (w >> 1) * 32;
  const int wn   = (w & 1) * 64;

  const int strow = tid >> 3;
  const int gl = ((tid & 7) ^ (strow & 7)) * 8;

  f4v acc[2][4];
#pragma unroll
  for (int i = 0; i < 2; ++i)
#pragma unroll
    for (int j = 0; j < 4; ++j)
#pragma unroll
      for (int r = 0; r < 4; ++r) acc[i][j][r] = 0.0f;

  const short* Ag = A + (size_t)(m0 + strow) * S_LEN + gl;
  const short* Bg = B + (size_t)(n0 + strow) * S_LEN + gl;
  const size_t pstr = (size_t)32 * S_LEN;
  const int t8 = tid * 8;
  const int swq = l16 & 7;

  const unsigned base = lds_addr(SMEM);
  unsigned aoff[2], boff[4];
#pragma unroll
  for (int ii = 0; ii < 2; ++ii)
    aoff[ii] = base + (unsigned)((wm + ii * 16 + l16) * 128 + ((quad ^ swq) * 16));
#pragma unroll
  for (int j = 0; j < 4; ++j)
    boff[j] = base + 8192u + (unsigned)((wn + j * 16 + l16) * 128 + ((quad ^ swq) * 16));

  const int niter = mi + 1;   // K runs 0 .. m0+64

  // preload tiles 0,1 into bufs 0,1 (6 loads each: A x2, B x4)
#pragma unroll
  for (int pre = 0; pre < 2; ++pre) {
    short* dst = SMEM + pre * 12288 + t8;
    const int k0 = pre << 6;
#pragma unroll
    for (int p = 0; p < 2; ++p) glds16(Ag + k0 + p * pstr, dst + p * 2048);
#pragma unroll
    for (int p = 0; p < 4; ++p) glds16(Bg + k0 + p * pstr, dst + 4096 + p * 2048);
  }

  int cbuf = 0;
  for (int i = 0; i < niter; ++i) {
    if (i + 1 < niter) { WAITV(6); } else { WAITV(0); }   // tile i landed
    SBAR();
    SCHEDB();

    if (i + 2 < niter) {          // issue i+2 into the buffer read at i-1
      int nb = cbuf + 2; if (nb >= 3) nb -= 3;
      const int k2 = (i + 2) << 6;
      short* dst = SMEM + nb * 12288 + t8;
#pragma unroll
      for (int p = 0; p < 2; ++p) glds16(Ag + k2 + p * pstr, dst + p * 2048);
#pragma unroll
      for (int p = 0; p < 4; ++p) glds16(Bg + k2 + p * pstr, dst + 4096 + p * 2048);
      SCHEDB();
    }

    const unsigned cofs = (unsigned)(cbuf * 24576);
    cbuf = (cbuf == 2) ? 0 : cbuf + 1;
#pragma unroll
    for (int kk = 0; kk < 2; ++kk) {
      const unsigned kx = (unsigned)(kk << 6);
      s8v af[2], bf[4];
#pragma unroll
      for (int ii = 0; ii < 2; ++ii) af[ii] = dsr128((aoff[ii] ^ kx) + cofs);
#pragma unroll
      for (int j = 0; j < 4; ++j)   bf[j]  = dsr128((boff[j] ^ kx) + cofs);
      WAITL0();
      SCHEDB();
      __builtin_amdgcn_s_setprio(1);
#pragma unroll
      for (int ii = 0; ii < 2; ++ii)
#pragma unroll
        for (int j = 0; j < 4; ++j)
          acc[ii][j] = __builtin_amdgcn_mfma_f32_16x16x32_bf16(af[ii], bf[j], acc[ii][j], 0, 0, 0);
      __builtin_amdgcn_s_setprio(0);
    }
  }

  float* Cf = out + (size_t)bz * S_LEN * D_DIM;
#pragma unroll
  for (int i = 0; i < 2; ++i) {
#pragma unroll
    for (int j = 0; j < 4; ++j) {
      const int gn = n0 + wn + j * 16 + l16;
      const float tvn = Tv[(bz << 9) + gn];
#pragma unroll
      for (int r = 0; r < 4; ++r) {
        const int gm = m0 + wm + i * 16 + quad * 4 + r;
        Cf[(size_t)gm * D_DIM + gn] = acc[i][j][r] + tvn;
      }
    }
  }
}

// fp32 -> bf16, one launch for data (x<2048) and weights (x>=2048); zeroes ZF.
__global__ __launch_bounds__(256) void cvt_all(
    const float* __restrict__ q, const float* __restrict__ k, const float* __restrict__ v,
    const float* __restrict__ wq, const float* __restrict__ wk, const float* __restrict__ wv,
    short* __restrict__ qb, short* __restrict__ kb, short* __restrict__ vb,
    short* __restrict__ Wqb, short* __restrict__ Wkb, short* __restrict__ Wvb,
    float* __restrict__ ZF)
{
  const int y = blockIdx.y;
  const float* s; short* d; int i;
  if (blockIdx.x < 2048) {
    s = (y == 0) ? q : (y == 1) ? k : v;
    d = (y == 0) ? qb : (y == 1) ? kb : vb;
    i = (blockIdx.x * 256 + threadIdx.x) * 8;
    if (y == 0) {
      const int gid = blockIdx.x * 256 + threadIdx.x;
      if (gid < 8192) ZF[gid] = 0.0f;
    }
  } else {
    s = (y == 0) ? wq : (y == 1) ? wk : wv;
    d = (y == 0) ? Wqb : (y == 1) ? Wkb : Wvb;
    i = ((int)(blockIdx.x - 2048) * 256 + threadIdx.x) * 8;
  }
  const float4 f0 = *(const float4*)(s + i);
  const float4 f1 = *(const float4*)(s + i + 4);
  s8v o;
  o[0] = f2bf_s(f0.x); o[1] = f2bf_s(f0.y); o[2] = f2bf_s(f0.z); o[3] = f2bf_s(f0.w);
  o[4] = f2bf_s(f1.x); o[5] = f2bf_s(f1.y); o[6] = f2bf_s(f1.z); o[7] = f2bf_s(f1.w);
  *(s8v*)(d + i) = o;
}

// block per (b,d): vpT[b][d][k] /= (2048+ZF[b][k]); Tv[b,d] = sum_k (fp32)
__global__ __launch_bounds__(256) void scale_vpt_T(
    short* __restrict__ vpT, const float* __restrict__ ZF, float* __restrict__ Tv)
{
  __shared__ float red[4];
  const int b = blockIdx.y, d = blockIdx.x, tid = threadIdx.x;
  const size_t rowbase = ((size_t)(b * D_DIM + d)) * S_LEN;
  const float* zf = ZF + (b << 11);
  const int k0 = tid * 8;

  s8v v = *(s8v*)&vpT[rowbase + k0];
  float s = 0.0f;
#pragma unroll
  for (int i = 0; i < 8; ++i) {
    const float w = bf2f_s(v[i]) / (2048.0f + zf[k0 + i]);
    s += w;
    v[i] = f2bf_s(w);
  }
  *(s8v*)&vpT[rowbase + k0] = v;

#pragma unroll
  for (int off = 32; off >= 1; off >>= 1) s += __shfl_xor(s, off, 64);
  if ((tid & 63) == 0) red[tid >> 6] = s;
  __syncthreads();
  if (tid == 0) Tv[(b << 9) + d] = red[0] + red[1] + red[2] + red[3];
}

extern "C" void kernel_launch(void* const* d_in, const int* in_sizes, int n_in,
                              void* d_out, int out_size, void* d_ws, size_t ws_size,
                              hipStream_t stream) {
  const float* q   = (const float*)d_in[0];
  const float* k   = (const float*)d_in[1];
  const float* v   = (const float*)d_in[2];
  const float* WQw = (const float*)d_in[3];
  const float* WQb = (const float*)d_in[4];
  const float* WKw = (const float*)d_in[5];
  const float* WKb = (const float*)d_in[6];
  const float* WVw = (const float*)d_in[7];
  const float* WVb = (const float*)d_in[8];

  char* ws = (char*)d_ws;
  // F occupies ws[0,32M); bf16 input/weight copies alias its head — all of
  // proj256 completes before scores256 writes any F byte.
  short* F   = (short*)(ws);                 // 32 MB  [4][2048][2048] (lower tiles only)
  short* qb  = (short*)(ws);                 //  8 MB  (alias F)
  short* kb  = qb + 4194304;                 //  8 MB
  short* vb  = qb + 8388608;                 //  8 MB
  short* Wqb = (short*)(ws + 25165824);      //  512 KB
  short* Wkb = Wqb + 262144;
  short* Wvb = Wqb + 524288;
  short* qp  = (short*)(ws + 33554432);      //  8 MB  [4][2048][512]
  short* kp  = (short*)(ws + 41943040);      //  8 MB
  short* vpT = (short*)(ws + 50331648);      //  8 MB  [4][512][2048]
  float* ZF  = (float*)(ws + 58720256);      // 32 KB  [4][2048]
  float* Tv  = (float*)(ws + 58753024);      //  8 KB  [4][512]

  // allow 128 KB dynamic LDS on the 256^2 kernels (one-time host calls)
  static bool attr_done = false;
  if (!attr_done) {
    (void)hipFuncSetAttribute((const void*)proj256,
                              hipFuncAttributeMaxDynamicSharedMemorySize, 131072);
    (void)hipFuncSetAttribute((const void*)scores256,
                              hipFuncAttributeMaxDynamicSharedMemorySize, 131072);
    attr_done = true;
  }

  const dim3 blk(256);

  cvt_all<<<dim3(2176, 3), blk, 0, stream>>>(
      q, k, v, WQw, WKw, WVw, qb, kb, vb, Wqb, Wkb, Wvb, ZF);

  // all three projections: 192 blocks x 512 threads, 128 KB LDS, 1/CU
  proj256<<<dim3(192), dim3(512), 131072, stream>>>(
      qb, kb, vb, Wqb, Wkb, Wvb, qp, kp, vpT, WQb, WKb, WVb);

  // F = expm1(scale*qp@kp^T) lower-tri 256-tiles + fused ZF colsum
  scores256<<<dim3(144), dim3(512), 131072, stream>>>(qp, kp, F, ZF);

  // vpT' = vpT/(2048+ZF); Tv = rowsum(vpT')
  scale_vpt_T<<<dim3(512, 4), blk, 0, stream>>>(vpT, ZF, Tv);

  // out = F @ vpT'^T + Tv: 64x128 tiles, K truncated at m0+64, balanced pairs
  gemm_outF<<<dim3(512), blk, 0, stream>>>(F, vpT, Tv, (float*)d_out);
}

// Round 13
// 162.415 us; speedup vs baseline: 1.1072x; 1.1072x over previous
//
#include <hip/hip_runtime.h>
#include <hip/hip_bf16.h>

// B=4, S=2048, D=512. fp32 in/out, bf16 MFMA internals.
// Key identity: multiplicative causal mask => E = 1 + F, F = expm1(scale*s) on
// the lower triangle (q>=k), 0 above. Then
//   out  = F @ vp'  +  T,   T[b,d] = sum_k vp'[b,k,d]
//   Z[k] = 2048 + colsum(F)
// Pipeline: cvt_all(+ZF0) | proj_qk | scores_projv | scaleT | outF
//
// R12: revert R11's 256^2 core (regressed +15us: block time scales with bytes
//      staged, not MFMA count; 1 block/CU lost inter-block overlap). Base =
//      R10 (best, 164.4us). One isolated change: outF XCD-aware mapping
//      (x=h&7 = XCD, s=h>>3 -> n0/bz/zslot, zs from (x,zslot)) so the 4
//      n-tiles sharing an F panel (and the 4 zslots sharing a vpT panel) land
//      on ONE XCD -> F (34MB > L2) fetched ~1x per XCD instead of 4x from
//      HBM. Per-XCD K-work stays balanced: each (n0,bz) group contributes
//      niter sum 66 on every XCD. All else byte-identical to R10.

#define S_LEN 2048
#define D_DIM 512
#define SCALE_F 0.044194173824159216f  // 1/sqrt(512)

typedef __attribute__((ext_vector_type(8))) short s8v;   // 8 bf16 = 4 VGPRs
typedef __attribute__((ext_vector_type(4))) short s4v;   // 4 bf16 = 8 B
typedef __attribute__((ext_vector_type(4))) float f4v;   // MFMA accumulator

enum { EPI_BIAS = 0, EPI_BIAS_T = 1, EPI_SCORES = 2 };

#define SBAR()    __builtin_amdgcn_s_barrier()
#define SCHEDB()  __builtin_amdgcn_sched_barrier(0)
#define WAITV(n)  asm volatile("s_waitcnt vmcnt(" #n ")")
#define WAITL0()  asm volatile("s_waitcnt lgkmcnt(0)")

__device__ __forceinline__ short f2bf_s(float f) {
  union { __hip_bfloat16 b; short s; } u; u.b = __float2bfloat16(f); return u.s;
}
__device__ __forceinline__ float bf2f_s(short h) {
  union { short s; __hip_bfloat16 b; } u; u.s = h; return __bfloat162float(u.b);
}

__device__ __forceinline__ void glds16(const short* g, short* l) {
  __builtin_amdgcn_global_load_lds((const __attribute__((address_space(1))) void*)g,
                                   (__attribute__((address_space(3))) void*)l, 16, 0, 0);
}

// LDS byte offset of a __shared__-derived pointer (addrspace(3) is 32-bit).
__device__ __forceinline__ unsigned lds_addr(const short* p) {
  return (unsigned)(unsigned long long)(const __attribute__((address_space(3))) short*)p;
}

// Inline-asm ds_read_b128: keeps the counted WAITV authoritative. MUST be
// followed by lgkmcnt(0)+SCHEDB before any consumer (rule 18).
__device__ __forceinline__ s8v dsr128(unsigned a) {
  s8v r;
  asm volatile("ds_read_b128 %0, %1" : "=&v"(r) : "v"(a));
  return r;
}

// ---------------------------------------------------------------------------
// Core NT GEMM, 128x128 tile at (m0,n0), BK=64, LDS double buffer (64 KB).
// Per iter: stage i+1 -> counted WAITV(8) (tile i landed, i+1 in flight) ->
// SBAR -> 2 phases {asm ds_read, lgkmcnt(0), setprio(1), 16 MFMA} -> SBAR.
template <int EPI>
__device__ __forceinline__ void gemm_core(
    const short* __restrict__ A, const short* __restrict__ B,
    short* __restrict__ C, const float* __restrict__ bias,
    short* SMEM, int N, int K, size_t sCz, int m0, int n0, int bz,
    float* __restrict__ Z)
{
  const int tid  = threadIdx.x;
  const int w    = tid >> 6;
  const int lane = tid & 63;
  const int quad = lane >> 4;
  const int l16  = lane & 15;
  const int wm   = (w >> 1) * 64;
  const int wn   = (w & 1) * 64;

  const int strow = tid >> 3;                         // 0..31
  const int gl = ((tid & 7) ^ (strow & 7)) * 8;       // XOR column-octet swizzle

  f4v acc[4][4];
#pragma unroll
  for (int i = 0; i < 4; ++i)
#pragma unroll
    for (int j = 0; j < 4; ++j)
#pragma unroll
      for (int r = 0; r < 4; ++r) acc[i][j][r] = 0.0f;

  const short* Ag = A + (size_t)(m0 + strow) * K + gl;
  const short* Bg = B + (size_t)(n0 + strow) * K + gl;
  const size_t pstr = (size_t)32 * K;
  const int t8 = tid * 8;
  const int swq = l16 & 7;

  const unsigned base = lds_addr(SMEM);
  unsigned aoff[4], boff[4];
#pragma unroll
  for (int ii = 0; ii < 4; ++ii)
    aoff[ii] = base + (unsigned)((wm + ii * 16 + l16) * 128 + ((quad ^ swq) * 16));
#pragma unroll
  for (int j = 0; j < 4; ++j)
    boff[j] = base + 16384u + (unsigned)((wn + j * 16 + l16) * 128 + ((quad ^ swq) * 16));

  const int niter = K >> 6;

#pragma unroll
  for (int p = 0; p < 4; ++p) glds16(Ag + p * pstr, SMEM + t8 + p * 2048);
#pragma unroll
  for (int p = 0; p < 4; ++p) glds16(Bg + p * pstr, SMEM + 8192 + t8 + p * 2048);

  for (int i = 0; i < niter; ++i) {
    const int c = i & 1;
    if (i + 1 < niter) {
      const int k1 = (i + 1) << 6;
      short* dA = SMEM + (1 - c) * 16384 + t8;
#pragma unroll
      for (int p = 0; p < 4; ++p) glds16(Ag + k1 + p * pstr, dA + p * 2048);
#pragma unroll
      for (int p = 0; p < 4; ++p) glds16(Bg + k1 + p * pstr, dA + 8192 + p * 2048);
      SCHEDB();
      WAITV(8);          // tile i landed; tile i+1's 8 stay in flight
    } else {
      WAITV(0);
    }
    SBAR();
    SCHEDB();

    const unsigned cofs = (unsigned)(c << 15);
#pragma unroll
    for (int kk = 0; kk < 2; ++kk) {
      const unsigned kx = (unsigned)(kk << 6);
      s8v af[4], bf[4];
#pragma unroll
      for (int ii = 0; ii < 4; ++ii) af[ii] = dsr128((aoff[ii] ^ kx) + cofs);
#pragma unroll
      for (int j = 0; j < 4; ++j)   bf[j]  = dsr128((boff[j] ^ kx) + cofs);
      WAITL0();
      SCHEDB();
      __builtin_amdgcn_s_setprio(1);
#pragma unroll
      for (int ii = 0; ii < 4; ++ii)
#pragma unroll
        for (int j = 0; j < 4; ++j)
          acc[ii][j] = __builtin_amdgcn_mfma_f32_16x16x32_bf16(af[ii], bf[j], acc[ii][j], 0, 0, 0);
      __builtin_amdgcn_s_setprio(0);
    }
    SBAR();              // buf c free for next iter's prefetch
  }

  // ---- epilogue ----
  float bv[4];
  if (EPI == EPI_BIAS || EPI == EPI_BIAS_T) {
#pragma unroll
    for (int j = 0; j < 4; ++j) bv[j] = bias[n0 + wn + j * 16 + l16];
  }

  if (EPI == EPI_BIAS_T) {
#pragma unroll
    for (int i = 0; i < 4; ++i) {
#pragma unroll
      for (int j = 0; j < 4; ++j) {
        const int gn  = n0 + wn + j * 16 + l16;
        const int gmb = m0 + wm + i * 16 + quad * 4;
        const int bb = gmb >> 11, ssb = gmb & (S_LEN - 1);
        s4v o;
#pragma unroll
        for (int r = 0; r < 4; ++r) o[r] = f2bf_s(acc[i][j][r] + bv[j]);
        *(s4v*)&C[((size_t)bb * D_DIM + gn) * S_LEN + ssb] = o;
      }
    }
    return;
  }

  // EPI_BIAS / EPI_SCORES: LDS transpose -> coalesced 16B row stores.
  short* TB = SMEM;                 // 4 waves x 2176 shorts (32 rows x stride 68)
  const int wbase = w * 2176;
  float csum[4] = {0.f, 0.f, 0.f, 0.f};

#pragma unroll
  for (int ph = 0; ph < 2; ++ph) {
    __syncthreads();
#pragma unroll
    for (int ii = 0; ii < 2; ++ii) {
      const int i = ph * 2 + ii;
#pragma unroll
      for (int j = 0; j < 4; ++j) {
        const int gn = n0 + wn + j * 16 + l16;
#pragma unroll
        for (int r = 0; r < 4; ++r) {
          short o;
          if (EPI == EPI_SCORES) {
            const int gm = m0 + wm + i * 16 + quad * 4 + r;
            const float f = (gm >= gn) ? (__expf(acc[i][j][r] * SCALE_F) - 1.0f) : 0.0f;
            csum[j] += f;
            o = f2bf_s(f);
          } else {
            o = f2bf_s(acc[i][j][r] + bv[j]);
          }
          TB[wbase + (ii * 16 + quad * 4 + r) * 68 + j * 16 + l16] = o;
        }
      }
    }
    __syncthreads();
#pragma unroll
    for (int p = 0; p < 4; ++p) {
      const int row = p * 8 + (lane >> 3);   // 0..31
      const int cg  = lane & 7;
      const s8v vv = *(const s8v*)&TB[wbase + row * 68 + cg * 8];
      const int gm = m0 + wm + ph * 32 + row;
      const int gn = n0 + wn + cg * 8;
      *(s8v*)&C[sCz + (size_t)gm * N + gn] = vv;
    }
  }

  if (EPI == EPI_SCORES) {
#pragma unroll
    for (int j = 0; j < 4; ++j) {
      float cs = csum[j];
      cs += __shfl_xor(cs, 16, 64);
      cs += __shfl_xor(cs, 32, 64);
      if (quad == 0) atomicAdd(&Z[(bz << 11) + n0 + wn + j * 16 + l16], cs);
    }
  }
}

// projections q,k only: 512 full tiles = exactly one dispatch round @2/CU.
__global__ __launch_bounds__(256, 2) void proj_qk(
    const short* __restrict__ a0, const short* __restrict__ a1,
    const short* __restrict__ b0, const short* __restrict__ b1,
    short* __restrict__ c0, short* __restrict__ c1,
    const float* __restrict__ x0, const float* __restrict__ x1)
{
  __shared__ __align__(16) short SMEM[32768];   // 64 KB
  const int bid = blockIdx.x;
  const int bsw = (bid & 7) * 64 + (bid >> 3);  // XCD-bijective (512 = 8x64)
  const int z   = bsw >> 8;                     // 0 or 1
  const int rem = bsw & 255;
  const int m0  = (rem >> 2) * 128;
  const int n0  = (rem & 3) * 128;
  const short* A = z ? a1 : a0;
  const short* B = z ? b1 : b0;
  short*       C = z ? c1 : c0;
  const float* bias = z ? x1 : x0;
  gemm_core<EPI_BIAS>(A, B, C, bias, SMEM, D_DIM, D_DIM, 0, m0, n0, 0, nullptr);
}

// Fused: 544 scores tiles (compact lower-tri, need qp/kp) + 256 vpT
// projection tiles (need only vb/Wvb, which live in d_out scratch — OUTSIDE
// F's region, so the concurrent F writes cannot clobber them). 800 blocks =
// 2 rounds; the vpT tiles fill scores' otherwise near-empty tail round.
__global__ __launch_bounds__(256, 2) void scores_projv(
    const short* __restrict__ qp, const short* __restrict__ kp, short* __restrict__ F,
    float* __restrict__ Z,
    const short* __restrict__ vb, const short* __restrict__ Wvb,
    short* __restrict__ vpT, const float* __restrict__ xv)
{
  __shared__ __align__(16) short SMEM[32768];   // 64 KB
  const int bid = blockIdx.x;
  if (bid < 544) {
    const int bsw = (bid & 7) * 68 + (bid >> 3);  // XCD-bijective (544 = 8x68)
    const int bz  = bsw / 136;
    const int t   = bsw - bz * 136;
    int ti = (int)((sqrtf(8.0f * t + 1.0f) - 1.0f) * 0.5f);
    while ((ti + 1) * (ti + 2) / 2 <= t) ++ti;
    while (ti * (ti + 1) / 2 > t) --ti;
    const int tj = t - ti * (ti + 1) / 2;         // tj <= ti
    gemm_core<EPI_SCORES>(qp + (size_t)bz * S_LEN * D_DIM, kp + (size_t)bz * S_LEN * D_DIM,
                          F, nullptr, SMEM, S_LEN, D_DIM,
                          (size_t)bz * S_LEN * S_LEN, ti * 128, tj * 128, bz, Z);
  } else {
    const int h   = bid - 544;                    // 0..255
    const int hsw = (h & 7) * 32 + (h >> 3);      // XCD-bijective (256 = 8x32)
    const int m0  = (hsw >> 2) * 128;             // 64 row-tiles of [8192]
    const int n0  = (hsw & 3) * 128;
    gemm_core<EPI_BIAS_T>(vb, Wvb, vpT, xv, SMEM, D_DIM, D_DIM, 0, m0, n0, 0, nullptr);
  }
}

// out = F @ vpT'^T + T, 64x128 tiles, BK=64, K truncated at m0+64,
// triple-buffered (72 KB), prefetch distance 2 issued AFTER the barrier.
// Grid 512 1-D, XCD-locality mapping: x=h&7 (XCD under round-robin), s=h>>3:
// n0=(s&3)*128, bz=(s>>2)&3, zslot=s>>4 (0..3),
// zs = zslot<2 ? 2x+zslot : 16+2x+(zslot-2), mi = zs<16 ? 31-zs : zs-16.
// The 4 n-tiles of one F panel (bz,mi) and the 4 zslots of one vpT panel
// (bz,n0) share an XCD; per-XCD K-work balanced (niter sum 66 per group).
__global__ __launch_bounds__(256, 2) void gemm_outF(
    const short* __restrict__ F, const short* __restrict__ vpT,
    const float* __restrict__ Tv, float* __restrict__ out)
{
  __shared__ __align__(16) short SMEM[36864];   // 72 KB

  const int tid  = threadIdx.x;
  const int h    = blockIdx.x;
  const int x    = h & 7;
  const int s    = h >> 3;
  const int n0   = (s & 3) * 128;
  const int bz   = (s >> 2) & 3;
  const int zslot = s >> 4;                     // 0..3
  const int zs   = (zslot < 2) ? (2 * x + zslot) : (16 + 2 * x + (zslot - 2));
  const int mi   = (zs < 16) ? (31 - zs) : (zs - 16);
  const int m0   = mi * 64;

  const short* A = F   + (size_t)bz * S_LEN * S_LEN;
  const short* B = vpT + (size_t)bz * D_DIM * S_LEN;

  const int w    = tid >> 6;
  const int lane = tid & 63;
  const int quad = lane >> 4;
  const int l16  = lane & 15;
  const int wm   = (w >> 1) * 32;
  const int wn   = (w & 1) * 64;

  const int strow = tid >> 3;
  const int gl = ((tid & 7) ^ (strow & 7)) * 8;

  f4v acc[2][4];
#pragma unroll
  for (int i = 0; i < 2; ++i)
#pragma unroll
    for (int j = 0; j < 4; ++j)
#pragma unroll
      for (int r = 0; r < 4; ++r) acc[i][j][r] = 0.0f;

  const short* Ag = A + (size_t)(m0 + strow) * S_LEN + gl;
  const short* Bg = B + (size_t)(n0 + strow) * S_LEN + gl;
  const size_t pstr = (size_t)32 * S_LEN;
  const int t8 = tid * 8;
  const int swq = l16 & 7;

  const unsigned base = lds_addr(SMEM);
  unsigned aoff[2], boff[4];
#pragma unroll
  for (int ii = 0; ii < 2; ++ii)
    aoff[ii] = base + (unsigned)((wm + ii * 16 + l16) * 128 + ((quad ^ swq) * 16));
#pragma unroll
  for (int j = 0; j < 4; ++j)
    boff[j] = base + 8192u + (unsigned)((wn + j * 16 + l16) * 128 + ((quad ^ swq) * 16));

  const int niter = mi + 1;   // K runs 0 .. m0+64

  // preload tiles 0,1 into bufs 0,1 (6 loads each: A x2, B x4)
#pragma unroll
  for (int pre = 0; pre < 2; ++pre) {
    short* dst = SMEM + pre * 12288 + t8;
    const int k0 = pre << 6;
#pragma unroll
    for (int p = 0; p < 2; ++p) glds16(Ag + k0 + p * pstr, dst + p * 2048);
#pragma unroll
    for (int p = 0; p < 4; ++p) glds16(Bg + k0 + p * pstr, dst + 4096 + p * 2048);
  }

  int cbuf = 0;
  for (int i = 0; i < niter; ++i) {
    if (i + 1 < niter) { WAITV(6); } else { WAITV(0); }   // tile i landed
    SBAR();
    SCHEDB();

    if (i + 2 < niter) {          // issue i+2 into the buffer read at i-1
      int nb = cbuf + 2; if (nb >= 3) nb -= 3;
      const int k2 = (i + 2) << 6;
      short* dst = SMEM + nb * 12288 + t8;
#pragma unroll
      for (int p = 0; p < 2; ++p) glds16(Ag + k2 + p * pstr, dst + p * 2048);
#pragma unroll
      for (int p = 0; p < 4; ++p) glds16(Bg + k2 + p * pstr, dst + 4096 + p * 2048);
      SCHEDB();
    }

    const unsigned cofs = (unsigned)(cbuf * 24576);
    cbuf = (cbuf == 2) ? 0 : cbuf + 1;
#pragma unroll
    for (int kk = 0; kk < 2; ++kk) {
      const unsigned kx = (unsigned)(kk << 6);
      s8v af[2], bf[4];
#pragma unroll
      for (int ii = 0; ii < 2; ++ii) af[ii] = dsr128((aoff[ii] ^ kx) + cofs);
#pragma unroll
      for (int j = 0; j < 4; ++j)   bf[j]  = dsr128((boff[j] ^ kx) + cofs);
      WAITL0();
      SCHEDB();
      __builtin_amdgcn_s_setprio(1);
#pragma unroll
      for (int ii = 0; ii < 2; ++ii)
#pragma unroll
        for (int j = 0; j < 4; ++j)
          acc[ii][j] = __builtin_amdgcn_mfma_f32_16x16x32_bf16(af[ii], bf[j], acc[ii][j], 0, 0, 0);
      __builtin_amdgcn_s_setprio(0);
    }
  }

  float* Cf = out + (size_t)bz * S_LEN * D_DIM;
#pragma unroll
  for (int i = 0; i < 2; ++i) {
#pragma unroll
    for (int j = 0; j < 4; ++j) {
      const int gn = n0 + wn + j * 16 + l16;
      const float tvn = Tv[(bz << 9) + gn];
#pragma unroll
      for (int r = 0; r < 4; ++r) {
        const int gm = m0 + wm + i * 16 + quad * 4 + r;
        Cf[(size_t)gm * D_DIM + gn] = acc[i][j][r] + tvn;
      }
    }
  }
}

// fp32 -> bf16, one launch for data (x<2048) and weights (x>=2048); zeroes ZF.
__global__ __launch_bounds__(256) void cvt_all(
    const float* __restrict__ q, const float* __restrict__ k, const float* __restrict__ v,
    const float* __restrict__ wq, const float* __restrict__ wk, const float* __restrict__ wv,
    short* __restrict__ qb, short* __restrict__ kb, short* __restrict__ vb,
    short* __restrict__ Wqb, short* __restrict__ Wkb, short* __restrict__ Wvb,
    float* __restrict__ ZF)
{
  const int y = blockIdx.y;
  const float* s; short* d; int i;
  if (blockIdx.x < 2048) {
    s = (y == 0) ? q : (y == 1) ? k : v;
    d = (y == 0) ? qb : (y == 1) ? kb : vb;
    i = (blockIdx.x * 256 + threadIdx.x) * 8;
    if (y == 0) {
      const int gid = blockIdx.x * 256 + threadIdx.x;
      if (gid < 8192) ZF[gid] = 0.0f;
    }
  } else {
    s = (y == 0) ? wq : (y == 1) ? wk : wv;
    d = (y == 0) ? Wqb : (y == 1) ? Wkb : Wvb;
    i = ((int)(blockIdx.x - 2048) * 256 + threadIdx.x) * 8;
  }
  const float4 f0 = *(const float4*)(s + i);
  const float4 f1 = *(const float4*)(s + i + 4);
  s8v o;
  o[0] = f2bf_s(f0.x); o[1] = f2bf_s(f0.y); o[2] = f2bf_s(f0.z); o[3] = f2bf_s(f0.w);
  o[4] = f2bf_s(f1.x); o[5] = f2bf_s(f1.y); o[6] = f2bf_s(f1.z); o[7] = f2bf_s(f1.w);
  *(s8v*)(d + i) = o;
}

// block per (b,d): vpT[b][d][k] /= (2048+ZF[b][k]); Tv[b,d] = sum_k (fp32)
__global__ __launch_bounds__(256) void scale_vpt_T(
    short* __restrict__ vpT, const float* __restrict__ ZF, float* __restrict__ Tv)
{
  __shared__ float red[4];
  const int b = blockIdx.y, d = blockIdx.x, tid = threadIdx.x;
  const size_t rowbase = ((size_t)(b * D_DIM + d)) * S_LEN;
  const float* zf = ZF + (b << 11);
  const int k0 = tid * 8;

  s8v v = *(s8v*)&vpT[rowbase + k0];
  float s = 0.0f;
#pragma unroll
  for (int i = 0; i < 8; ++i) {
    const float w = bf2f_s(v[i]) / (2048.0f + zf[k0 + i]);
    s += w;
    v[i] = f2bf_s(w);
  }
  *(s8v*)&vpT[rowbase + k0] = v;

#pragma unroll
  for (int off = 32; off >= 1; off >>= 1) s += __shfl_xor(s, off, 64);
  if ((tid & 63) == 0) red[tid >> 6] = s;
  __syncthreads();
  if (tid == 0) Tv[(b << 9) + d] = red[0] + red[1] + red[2] + red[3];
}

extern "C" void kernel_launch(void* const* d_in, const int* in_sizes, int n_in,
                              void* d_out, int out_size, void* d_ws, size_t ws_size,
                              hipStream_t stream) {
  const float* q   = (const float*)d_in[0];
  const float* k   = (const float*)d_in[1];
  const float* v   = (const float*)d_in[2];
  const float* WQw = (const float*)d_in[3];
  const float* WQb = (const float*)d_in[4];
  const float* WKw = (const float*)d_in[5];
  const float* WKb = (const float*)d_in[6];
  const float* WVw = (const float*)d_in[7];
  const float* WVb = (const float*)d_in[8];

  char* ws = (char*)d_ws;
  // F occupies ws[0,32M). qb/kb/Wqb/Wkb alias F (dead before any F write).
  // vb and Wvb must SURVIVE into scores_projv (concurrent with F writes), so
  // they live in d_out scratch: out is 16MB and only written by the final
  // outF phase, which fully overwrites it.
  short* F   = (short*)(ws);                 // 32 MB  [4][2048][2048] (lower tiles only)
  short* qb  = (short*)(ws);                 //  8 MB  (alias F, dead after proj_qk)
  short* kb  = qb + 4194304;                 //  8 MB  (alias F)
  short* Wqb = (short*)(ws + 25165824);      //  512 KB (alias F, dead after proj_qk)
  short* Wkb = Wqb + 262144;                 //  512 KB (alias F)
  short* qp  = (short*)(ws + 33554432);      //  8 MB  [4][2048][512]
  short* kp  = (short*)(ws + 41943040);      //  8 MB
  short* vpT = (short*)(ws + 50331648);      //  8 MB  [4][512][2048]
  float* ZF  = (float*)(ws + 58720256);      // 32 KB  [4][2048]
  float* Tv  = (float*)(ws + 58753024);      //  8 KB  [4][512]
  short* vb  = (short*)d_out;                //  8 MB  (out scratch [0,8M))
  short* Wvb = (short*)d_out + 4194304;      //  512 KB (out scratch [8M,8.5M))

  const dim3 blk(256);

  cvt_all<<<dim3(2176, 3), blk, 0, stream>>>(
      q, k, v, WQw, WKw, WVw, qb, kb, vb, Wqb, Wkb, Wvb, ZF);

  // q,k projections: 512 full tiles = exactly one round @2/CU
  proj_qk<<<dim3(512), blk, 0, stream>>>(qb, kb, Wqb, Wkb, qp, kp, WQb, WKb);

  // scores (544) + independent vpT projection (256) fused: 2 rounds
  scores_projv<<<dim3(800), blk, 0, stream>>>(qp, kp, F, ZF, vb, Wvb, vpT, WVb);

  // vpT' = vpT/(2048+ZF); Tv = rowsum(vpT')
  scale_vpt_T<<<dim3(512, 4), blk, 0, stream>>>(vpT, ZF, Tv);

  // out = F @ vpT'^T + Tv: 64x128 tiles, K truncated at m0+64, XCD-local
  gemm_outF<<<dim3(512), blk, 0, stream>>>(F, vpT, Tv, (float*)d_out);
}